// Round 5
// baseline (398.904 us; speedup 1.0000x reference)
//
#include <hip/hip_runtime.h>
#include <stdint.h>

// ---------------------------------------------------------------------------
// torch-ngp hashgrid encode (16 levels, dim 2) + 32->64->8 ReLU MLP + 8-corner
// trilinear blend.  Layer 1 on f16 MFMA with hi/lo compensation (f32 accum);
// h round-trips LDS as PLAIN F32 via the HW-verified C/D layout; layer 2 and
// the corner blend are scalar f32 (identical to the round-1 kernel that
// passed).  One thread per (point, outer corner); wave owns 8 points.
// All LDS regions are wave-private -> no __syncthreads needed.
// ---------------------------------------------------------------------------

#define BLK 256
#define R15 513          // ceil(16*scale^15); verified in round 1
#define WSTRIDE 9216     // per-wave LDS region bytes

typedef _Float16 half8  __attribute__((ext_vector_type(8)));
typedef _Float16 half2v __attribute__((ext_vector_type(2)));
typedef float    floatx4 __attribute__((ext_vector_type(4)));

__device__ __forceinline__ void split16(float x, _Float16& hi, _Float16& lo) {
  hi = (_Float16)x;                 // RNE
  lo = (_Float16)(x - (float)hi);   // x-hi exact in f32
}

// feats LDS layout (per wave region): 16B chunks, lin = ((row>>4)*4+q)*16+(row&15)
//   hi chunk at lin*16, lo chunk at 4096 + lin*16.
// Per-level store: level l -> chunk q = l>>2, pair offset (l&3)*4 bytes.
__device__ __forceinline__ void store_feat(char* wb, int lane, int l,
                                           float a0, float a1) {
  _Float16 h0, l0, h1, l1;
  split16(a0, h0, l0);
  split16(a1, h1, l1);
  int lin = ((lane >> 4) * 4 + (l >> 2)) * 16 + (lane & 15);
  int off = lin * 16 + (l & 3) * 4;
  *(half2v*)(wb + off)        = (half2v){h0, h1};
  *(half2v*)(wb + 4096 + off) = (half2v){l0, l1};
}

// Linear (tight-grid) level: compile-time R/H/O so % H becomes magic-multiply.
// NOTE: %H is required -- corner coords reach R+1 when x==1.0, id overflows H.
template <int R, int H, int O>
__device__ __forceinline__ void enc_linear(float xcx, float xcy, float xcz,
                                           const float2* __restrict__ tab,
                                           float& o0, float& o1) {
  const float Rf = (float)R;
  float px = __fadd_rn(__fmul_rn(xcx, Rf), 0.5f);
  float py = __fadd_rn(__fmul_rn(xcy, Rf), 0.5f);
  float pz = __fadd_rn(__fmul_rn(xcz, Rf), 0.5f);
  float fpx = floorf(px), fpy = floorf(py), fpz = floorf(pz);
  float frx = px - fpx, fry = py - fpy, frz = pz - fpz;
  int gx = (int)fpx, gy = (int)fpy, gz = (int)fpz;
  int ty0 = gy * (R + 1), ty1 = ty0 + (R + 1);
  int tz0 = gz * ((R + 1) * (R + 1)), tz1 = tz0 + (R + 1) * (R + 1);
  float wx[2] = {1.f - frx, frx};
  float wy[2] = {1.f - fry, fry};
  float wz[2] = {1.f - frz, frz};
  float a0 = 0.f, a1 = 0.f;
#pragma unroll
  for (int c = 0; c < 8; ++c) {  // corner bits (x,y,z)=(2,1,0): CORNERS order
    const int ox = (c >> 2) & 1, oy = (c >> 1) & 1, oz = c & 1;
    int id  = (gx + ox) + (oy ? ty1 : ty0) + (oz ? tz1 : tz0);
    int idx = id % H;
    float w = wx[ox] * wy[oy] * wz[oz];
    float2 tv = tab[O + idx];
    a0 = fmaf(w, tv.x, a0);
    a1 = fmaf(w, tv.y, a1);
  }
  o0 = a0; o1 = a1;
}

__global__ __launch_bounds__(BLK, 3)
void grid_fused(const float* __restrict__ xyz, const float* __restrict__ bound,
                const float* __restrict__ table, const float* __restrict__ w1,
                const float* __restrict__ w2, float* __restrict__ out) {
  __shared__ __align__(16) char smem[36864];

  const int tid  = threadIdx.x;
  const int lane = tid & 63;
  const int wv   = tid >> 6;
  const int t    = blockIdx.x * BLK + tid;
  const int p    = t >> 3;
  const int a    = t & 7;

  const float2* tab = (const float2*)table;
  char* wb = smem + wv * WSTRIDE;

  // ---- outer corner setup ------------------------------------------------
  const float b = bound[0];
  float X = xyz[3 * p + 0], Y = xyz[3 * p + 1], Z = xyz[3 * p + 2];
  float cx = ((X + b) / (2.0f * b)) * 512.0f;
  float cy = ((Y + b) / (2.0f * b)) * 512.0f;
  float cz = ((Z + b) / (2.0f * b)) * 512.0f;
  float c0x = fmaxf(fminf(floorf(cx), 511.f), 0.f);
  float c0y = fmaxf(fminf(floorf(cy), 511.f), 0.f);
  float c0z = fmaxf(fminf(floorf(cz), 511.f), 0.f);
  float uu = cx - c0x, vv = cy - c0y, wwf = cz - c0z;

  const int ax = (a >> 2) & 1, ay = (a >> 1) & 1, az = a & 1;
  float xcx = (c0x + (float)ax) * (1.0f / 512.0f);
  float xcy = (c0y + (float)ay) * (1.0f / 512.0f);
  float xcz = (c0z + (float)az) * (1.0f / 512.0f);

  // ---- encode: 7 linear + 9 hashed levels, f32, stored hi/lo to LDS ------
  {
    float f0, f1;
    enc_linear<16,   4920,      0>(xcx, xcy, xcz, tab, f0, f1); store_feat(wb, lane, 0, f0, f1);
    enc_linear<21,  10648,   4920>(xcx, xcy, xcz, tab, f0, f1); store_feat(wb, lane, 1, f0, f1);
    enc_linear<26,  19688,  15568>(xcx, xcy, xcz, tab, f0, f1); store_feat(wb, lane, 2, f0, f1);
    enc_linear<33,  39304,  35256>(xcx, xcy, xcz, tab, f0, f1); store_feat(wb, lane, 3, f0, f1);
    enc_linear<41,  74088,  74560>(xcx, xcy, xcz, tab, f0, f1); store_feat(wb, lane, 4, f0, f1);
    enc_linear<51, 140608, 148648>(xcx, xcy, xcz, tab, f0, f1); store_feat(wb, lane, 5, f0, f1);
    enc_linear<65, 287496, 289256>(xcx, xcy, xcz, tab, f0, f1); store_feat(wb, lane, 6, f0, f1);
  }

  constexpr int   hO[9] = {576752, 1101040, 1625328, 2149616, 2673904,
                           3198192, 3722480, 4246768, 4771056};
  constexpr float hR[9] = {81.f, 102.f, 129.f, 162.f, 204.f, 257.f,
                           324.f, 408.f, (float)R15};
#pragma unroll
  for (int l = 0; l < 9; ++l) {
    const float Rf = hR[l];
    const int   O  = hO[l];
    float px = __fadd_rn(__fmul_rn(xcx, Rf), 0.5f);
    float py = __fadd_rn(__fmul_rn(xcy, Rf), 0.5f);
    float pz = __fadd_rn(__fmul_rn(xcz, Rf), 0.5f);
    float fpx = floorf(px), fpy = floorf(py), fpz = floorf(pz);
    float frx = px - fpx, fry = py - fpy, frz = pz - fpz;
    uint32_t gx = (uint32_t)(int)fpx, gy = (uint32_t)(int)fpy, gz = (uint32_t)(int)fpz;
    uint32_t hy0 = gy * 2654435761u, hy1 = (gy + 1u) * 2654435761u;
    uint32_t hz0 = gz * 805459861u,  hz1 = (gz + 1u) * 805459861u;
    float wx[2] = {1.f - frx, frx};
    float wy[2] = {1.f - fry, fry};
    float wz[2] = {1.f - frz, frz};
    float a0 = 0.f, a1 = 0.f;
#pragma unroll
    for (int c = 0; c < 8; ++c) {
      const int ox = (c >> 2) & 1, oy = (c >> 1) & 1, oz = c & 1;
      uint32_t idx = ((gx + (uint32_t)ox) ^ (oy ? hy1 : hy0) ^ (oz ? hz1 : hz0))
                     & 524287u;
      float w = wx[ox] * wy[oy] * wz[oz];
      float2 tv = tab[O + (int)idx];
      a0 = fmaf(w, tv.x, a0);
      a1 = fmaf(w, tv.y, a1);
    }
    store_feat(wb, lane, 7 + l, a0, a1);
  }

  const int col  = lane & 15;
  const int quad = lane >> 4;

  // ---- A-frags (layer 1), hi+lo: A[m=col][k=quad*8+j] per 16-row block ----
  half8 ahi[4], alo[4];
#pragma unroll
  for (int r = 0; r < 4; ++r) {
    int off = ((r * 4 + quad) * 16 + col) * 16;
    ahi[r] = *(const half8*)(wb + off);
    alo[r] = *(const half8*)(wb + 4096 + off);
  }
  __builtin_amdgcn_wave_barrier();  // frag reads before hbuf overwrites feats

  // ---- B-frags hi/lo: w1 [32][64] ----------------------------------------
  half8 b1hi[4], b1lo[4];
#pragma unroll
  for (int nt = 0; nt < 4; ++nt)
#pragma unroll
    for (int j = 0; j < 8; ++j) {
      _Float16 hi, lo;
      split16(w1[(quad * 8 + j) * 64 + nt * 16 + col], hi, lo);
      b1hi[nt][j] = hi; b1lo[nt][j] = lo;
    }

  // ---- layer 1 (compensated MFMA) -> f32 h to LDS -> scalar layer 2 ------
  // hbuf: f32 [64 rows][32 cols + 4 pad], stride 36 dwords (=144 B, 16B-
  // aligned rows).  Written via the HW-verified C/D mapping
  // (row = quad*4+i, col = lane&15); read back by each thread as ITS OWN
  // row (no fragment-layout assumption).  Aliases the feats region.
  float* hbuf = (float*)wb;
  float acc[8] = {0.f, 0.f, 0.f, 0.f, 0.f, 0.f, 0.f, 0.f};

#pragma unroll
  for (int hf = 0; hf < 2; ++hf) {
#pragma unroll
    for (int r = 0; r < 4; ++r) {
#pragma unroll
      for (int tt = 0; tt < 2; ++tt) {
        const int nt = 2 * hf + tt;
        floatx4 d = __builtin_amdgcn_mfma_f32_16x16x32_f16(
            ahi[r], b1hi[nt], (floatx4){0.f, 0.f, 0.f, 0.f}, 0, 0, 0);
        d = __builtin_amdgcn_mfma_f32_16x16x32_f16(ahi[r], b1lo[nt], d, 0, 0, 0);
        d = __builtin_amdgcn_mfma_f32_16x16x32_f16(alo[r], b1hi[nt], d, 0, 0, 0);
#pragma unroll
        for (int i = 0; i < 4; ++i)
          hbuf[(r * 16 + quad * 4 + i) * 36 + tt * 16 + col] = d[i];
      }
    }
    __builtin_amdgcn_wave_barrier();  // h writes before own-row reads
    // scalar layer 2 over this half's 32 hidden units (own row = lane)
    const char* hrow = wb + lane * 144;
#pragma unroll
    for (int c4 = 0; c4 < 8; ++c4) {
      floatx4 hv = *(const floatx4*)(hrow + c4 * 16);
#pragma unroll
      for (int e = 0; e < 4; ++e) {
        float hk = fmaxf(hv[e], 0.f);
        const float* w2r = w2 + (hf * 32 + c4 * 4 + e) * 8;  // uniform -> s_load
#pragma unroll
        for (int j = 0; j < 8; ++j) acc[j] = fmaf(hk, w2r[j], acc[j]);
      }
    }
    __builtin_amdgcn_wave_barrier();  // reads before next-half h writes
  }

  // ---- outer trilinear weight + 8-lane reduction (round-1 verified) ------
  float wt = (ax ? uu : 1.f - uu) * (ay ? vv : 1.f - vv) * (az ? wwf : 1.f - wwf);
#pragma unroll
  for (int j = 0; j < 8; ++j) {
    float v = acc[j] * wt;
    v += __shfl_xor(v, 1);
    v += __shfl_xor(v, 2);
    v += __shfl_xor(v, 4);
    acc[j] = v;  // all 8 lanes of the point now hold the full sum
  }
  float r01 = (a & 1) ? acc[1] : acc[0];
  float r23 = (a & 1) ? acc[3] : acc[2];
  float r45 = (a & 1) ? acc[5] : acc[4];
  float r67 = (a & 1) ? acc[7] : acc[6];
  float r03 = (a & 2) ? r23 : r01;
  float r47 = (a & 2) ? r67 : r45;
  float r   = (a & 4) ? r47 : r03;
  out[t] = r;  // out[p*8 + a], fully coalesced
}

extern "C" void kernel_launch(void* const* d_in, const int* in_sizes, int n_in,
                              void* d_out, int out_size, void* d_ws, size_t ws_size,
                              hipStream_t stream) {
  const float* xyz   = (const float*)d_in[0];
  const float* bound = (const float*)d_in[1];
  const float* table = (const float*)d_in[2];
  const float* w1    = (const float*)d_in[3];
  const float* w2    = (const float*)d_in[4];
  float* out = (float*)d_out;

  const int N = in_sizes[0] / 3;           // 262144 (multiple of 32)
  const int blocks = (N * 8) / BLK;        // 32 points per block
  grid_fused<<<blocks, BLK, 0, stream>>>(xyz, bound, table, w1, w2, out);
}